// Round 21
// baseline (42.366 us; speedup 1.0000x reference)
//
#include <hip/hip_runtime.h>
#include <stdint.h>

// DeformConv1d: x[8,256,4096] f32, offsets[8,1,4094,3] f32,
// weight[256,256,3] f32, bias[256] f32 -> out[8,256,4094] f32.
//
// R21: cheap staging AND cheap build AND phase overlap.
//  - Xt = transposed bf16 [68][128] swizzled window (R15's layout):
//    build = 4 x ds_read_b128 + interp (R15-proven, ~48cy/wave vs R20's
//    186cy scalar-gather build).
//  - Staging = burst-immediate (load 2 float4 groups -> f2bf -> 4 scalar
//    u16 swizzled writes each; no registers held across compute -> no
//    spills; R20 confirmed the no-spill FETCH/WRITE signature).
//  - Bp double-buffered: build(p+1) runs in the SAME phase as ksteps(p)
//    (waves skew across the missing barrier -> overlap). ch1 staging
//    overlaps ksteps(2). Pipeline:
//      pre : stage(ch0); bar; build(0)->Bp0; bar
//      p=0 : build(1)->Bp1 || ksteps(0)<-Bp0 ; bar
//      p=1 : build(2)->Bp0 || ksteps(1)<-Bp1 ; bar
//      p=2 : stage(ch1)    || ksteps(2)<-Bp0 ; bar
//      p=3 : build(3)->Bp1; bar; build(4)->Bp0 || ksteps(3)<-Bp1 ; bar
//      p=4 : build(5)->Bp1 || ksteps(4)<-Bp0 ; bar
//      p=5 : ksteps(5)<-Bp1 ; bar -> epilogue
//    Race check: each Bp buffer's writer is separated from its previous
//    readers by >=1 barrier; Xt writes (stage ch1, p=2) happen after
//    Xt's last reader (build(2), p=1) drained at the p=1 barrier.
// Unchanged: 32x32x16 MFMA, wave-private A from L2 + 1-step prefetch,
// register meta, LDS epilogue (WRITE == output), XCD decode, grid 512x512.

constexpr int CIN  = 256;
constexpr int LX   = 4096;
constexpr int KT   = 3;
constexpr int OUTL = 4094;
constexpr int COUT = 256;
constexpr int NQ   = 24;    // K-chunks of 32
constexpr int EPIW = 68;    // padded epilogue row (floats)
constexpr int NIT  = 2176;  // 128 c * 17 float4-groups per half
constexpr int BPH  = 8192;  // shorts per Bp buffer (64 x 128)

typedef __attribute__((ext_vector_type(8))) short bf16x8;
typedef __attribute__((ext_vector_type(4))) float f32x4;
typedef __attribute__((ext_vector_type(16))) float f32x16;

__device__ __forceinline__ short f2bf(float f) {        // round-half-up
  union { float f; uint32_t u; } v; v.f = f;
  return (short)((v.u + 0x8000u) >> 16);
}
__device__ __forceinline__ float bf2f(short s) {
  union { uint32_t u; float f; } v;
  v.u = ((uint32_t)(uint16_t)s) << 16;
  return v.f;
}
__device__ __forceinline__ float4 loadx4(const float* p, int l) {
  if (l + 3 < LX) return *(const float4*)(p + l);   // l is 16B-aligned
  float4 v; v.x = v.y = v.z = v.w = 0.f;
  if (l + 0 < LX) v.x = p[l + 0];
  if (l + 1 < LX) v.y = p[l + 1];
  if (l + 2 < LX) v.z = p[l + 2];
  return v;
}

// A pack: shorts idx = ((q*2+h)*8 + mf)*512 + l*8 + j   (same as R14+)
__global__ __launch_bounds__(256) void pack_weights_kernel(
    const float* __restrict__ w, short* __restrict__ ap) {
  const int gid = blockIdx.x * 256 + threadIdx.x;
  if (gid >= NQ * 2 * 8 * 64) return;
  const int l   = gid & 63;
  const int mf  = (gid >> 6) & 7;
  const int h   = (gid >> 9) & 1;
  const int q   = gid >> 10;
  const int ch  = q / 12;
  const int ks  = q % 12;
  const int tap = ks >> 2;
  const int c0  = ch * 128 + (ks & 3) * 32 + h * 16 + (l >> 5) * 8;
  const int row = mf * 32 + (l & 31);
  bf16x8 v;
  #pragma unroll
  for (int j = 0; j < 8; ++j) {
    v[j] = f2bf(w[((size_t)row * CIN + c0 + j) * KT + tap]);
  }
  *(bf16x8*)(ap + (size_t)gid * 8) = v;
}

__global__ __launch_bounds__(512, 4) void deform_gemm_kernel(
    const float* __restrict__ x, const float* __restrict__ off,
    const short* __restrict__ ap, const float* __restrict__ bias,
    float* __restrict__ out) {

  // arena: [0,17408) Xt bf16 [68][128] swz / Epi f32 64x68 (reuse),
  //        [17408,33792) Bp0, [33792,50176) Bp1, [50176,51200) biasS
  __shared__ __align__(16) char smem[17408 + 2 * 16384 + 1024];
  short* Xt    = (short*)smem;
  short* BpB   = (short*)(smem + 17408);
  float* Epi   = (float*)smem;
  float* biasS = (float*)(smem + 50176);

  const int tid  = threadIdx.x;
  const int lane = tid & 63;
  const int wid  = tid >> 6;       // 0..7 = M-frag index
  const int l31  = lane & 31;
  const int lh   = lane >> 5;      // k-half within fragment

  // decode: b in low 3 bits (XCD-chunk); th pairs at bid stride 8
  const int b    = blockIdx.x & 7;        // 8 batches
  const int rest = blockIdx.x >> 3;       // 0..63
  const int th   = rest & 1;              // t-half
  const int tt   = rest >> 1;             // 32 coarse t-tiles
  const int t0   = tt * 128 + th * 64;

  // ---- per-thread interp meta for the Bp build (t = t0 + (tid&63)) ----
  float w0m[3], w1m[3];
  int   d0m[3];
  {
    const int t = t0 + (tid & 63);
    #pragma unroll
    for (int k = 0; k < KT; ++k) {
      float w0 = 0.f, w1 = 0.f; int d0 = 0;
      if (t < OUTL) {
        const float o = off[((size_t)b * OUTL + t) * KT + k];
        float T = (float)(t + k) + o;
        T = fminf(fmaxf(T, (float)t), (float)(t + 2));  // clip to [t, t+2]
        int U0 = (int)T;                                 // floor (T >= 0)
        if (U0 > LX - 2) U0 = LX - 2;
        w1 = T - (float)U0;                              // in [0,1]
        w0 = 1.f - w1;
        d0 = U0 - t0;                                    // in [0, 66]
      }
      w0m[k] = w0; w1m[k] = w1; d0m[k] = d0;
    }
  }
  if (tid < COUT) biasS[tid] = bias[tid];

  f32x16 acc0 = {0.f,0.f,0.f,0.f,0.f,0.f,0.f,0.f,0.f,0.f,0.f,0.f,0.f,0.f,0.f,0.f};
  f32x16 acc1 = {0.f,0.f,0.f,0.f,0.f,0.f,0.f,0.f,0.f,0.f,0.f,0.f,0.f,0.f,0.f,0.f};

  const float* xb = x + (size_t)b * CIN * LX;

  // A: wave-private coalesced loads; preload step 0 (both K16 halves)
  const short* apw = ap + wid * 512 + lane * 8;
  bf16x8 aC0 = *(const bf16x8*)apw;
  bf16x8 aC1 = *(const bf16x8*)(apw + 4096);

  // ---- staging: burst-immediate transposed bf16 writes (no held regs) --
  auto stage = [&](int ch) {
    #pragma unroll
    for (int pr = 0; pr < 2; ++pr) {          // rounds {0,1}, {2,3}
      const int i0 = pr * 1024 + tid;
      const int i1 = i0 + 512;
      const int c0i = i0 / 17, g0 = i0 - c0i * 17;
      const int c1i = i1 / 17, g1 = i1 - c1i * 17;
      const float4 v0 = loadx4(xb + (size_t)(ch * 128 + c0i) * LX, t0 + 4 * g0);
      const float4 v1 = loadx4(xb + (size_t)(ch * 128 + c1i) * LX, t0 + 4 * g1);
      const float f0e[4] = {v0.x, v0.y, v0.z, v0.w};
      const float f1e[4] = {v1.x, v1.y, v1.z, v1.w};
      #pragma unroll
      for (int e = 0; e < 4; ++e) {
        const int p0 = g0 * 4 + e;
        Xt[(p0 * 128 + c0i) ^ ((p0 & 7) << 3)] = f2bf(f0e[e]);
      }
      #pragma unroll
      for (int e = 0; e < 4; ++e) {
        const int p1 = g1 * 4 + e;
        Xt[(p1 * 128 + c1i) ^ ((p1 & 7) << 3)] = f2bf(f1e[e]);
      }
    }
    {                                          // round 4 (tail, tid<128)
      const int i4 = 2048 + tid;
      if (i4 < NIT) {
        const int c = i4 / 17, g = i4 - c * 17;
        const float4 v = loadx4(xb + (size_t)(ch * 128 + c) * LX, t0 + 4 * g);
        const float fe[4] = {v.x, v.y, v.z, v.w};
        #pragma unroll
        for (int e = 0; e < 4; ++e) {
          const int pos = g * 4 + e;
          Xt[(pos * 128 + c) ^ ((pos & 7) << 3)] = f2bf(fe[e]);
        }
      }
    }
  };

  // ---- Bp build: R15-proven b128 path (TAP static for meta regs) ----
  auto build = [&](short* Bq, int tap) {
    const int tq = tid & 63;
    const int cb = (tid >> 6) * 16;
    const float w0 = w0m[tap], w1 = w1m[tap];
    const int   d0 = d0m[tap];
    const int sw0 = (d0 & 7) << 3;
    const int sw1 = ((d0 + 1) & 7) << 3;
    const int r0i = d0 * 128, r1i = (d0 + 1) * 128;
    const int swt = (tq & 7) << 3;
    {
      const bf16x8 r0a = *(const bf16x8*)&Xt[(r0i + cb) ^ sw0];
      const bf16x8 r1a = *(const bf16x8*)&Xt[(r1i + cb) ^ sw1];
      bf16x8 o1;
      #pragma unroll
      for (int j = 0; j < 8; ++j)
        o1[j] = f2bf(bf2f(r0a[j]) * w0 + bf2f(r1a[j]) * w1);
      *(bf16x8*)&Bq[(tq * 128 + cb) ^ swt] = o1;
    }
    {
      const bf16x8 r0b = *(const bf16x8*)&Xt[(r0i + cb + 8) ^ sw0];
      const bf16x8 r1b = *(const bf16x8*)&Xt[(r1i + cb + 8) ^ sw1];
      bf16x8 o2;
      #pragma unroll
      for (int j = 0; j < 8; ++j)
        o2[j] = f2bf(bf2f(r0b[j]) * w0 + bf2f(r1b[j]) * w1);
      *(bf16x8*)&Bq[(tq * 128 + cb + 8) ^ swt] = o2;
    }
  };

  // ---- K-steps: R20-verbatim (4 x K=32, A prefetch 1 ahead) ----
  auto ksteps = [&](const short* Bq, int p) {
    #pragma unroll 1
    for (int csub = 0; csub < 4; ++csub) {
      const int q  = p * 4 + csub;
      const int qn = q < NQ - 1 ? q + 1 : NQ - 1;
      const bf16x8 aN0 = *(const bf16x8*)(apw + (size_t)qn * 8192);
      const bf16x8 aN1 = *(const bf16x8*)(apw + (size_t)qn * 8192 + 4096);

      const int cbase = csub * 32 + lh * 8;
      const int ta = l31,      swa = (ta & 7) << 3;  // jn = 0
      const int tb = 32 + l31, swb = (tb & 7) << 3;  // jn = 1
      {
        const bf16x8 b00 = *(const bf16x8*)&Bq[(ta * 128 + cbase) ^ swa];
        const bf16x8 b10 = *(const bf16x8*)&Bq[(tb * 128 + cbase) ^ swb];
        acc0 = __builtin_amdgcn_mfma_f32_32x32x16_bf16(aC0, b00, acc0, 0, 0, 0);
        acc1 = __builtin_amdgcn_mfma_f32_32x32x16_bf16(aC0, b10, acc1, 0, 0, 0);
      }
      {
        const bf16x8 b01 = *(const bf16x8*)&Bq[(ta * 128 + cbase + 16) ^ swa];
        const bf16x8 b11 = *(const bf16x8*)&Bq[(tb * 128 + cbase + 16) ^ swb];
        acc0 = __builtin_amdgcn_mfma_f32_32x32x16_bf16(aC1, b01, acc0, 0, 0, 0);
        acc1 = __builtin_amdgcn_mfma_f32_32x32x16_bf16(aC1, b11, acc1, 0, 0, 0);
      }
      aC0 = aN0; aC1 = aN1;
    }
  };

  // ---- pipeline ----
  stage(0);
  __syncthreads();                 // Xt(ch0) + bias visible
  build(BpB, 0);                   // Bp0 <- (ch0,tap0)
  __syncthreads();

  #pragma unroll 1
  for (int ch = 0; ch < 2; ++ch) {
    // tap 0
    {
      const int p = ch * 3;
      short* cur = BpB + (p & 1) * BPH;
      short* nxt = BpB + ((p + 1) & 1) * BPH;
      if (ch == 1) {
        build(cur, 0);             // build(3): Xt(ch1) staged+visible
        __syncthreads();
      }
      build(nxt, 1);               // build(p+1) = tap1 of this ch
      ksteps(cur, p);
      __syncthreads();
    }
    // tap 1
    {
      const int p = ch * 3 + 1;
      short* cur = BpB + (p & 1) * BPH;
      short* nxt = BpB + ((p + 1) & 1) * BPH;
      if (ch == 0) build(nxt, 2);  // build(2); at ch1 p=4: build(5)=tap2
      else         build(nxt, 2);
      ksteps(cur, p);
      __syncthreads();
    }
    // tap 2
    {
      const int p = ch * 3 + 2;
      short* cur = BpB + (p & 1) * BPH;
      if (ch == 0) stage(1);       // Xt dead since p=1 barrier; overlap
      ksteps(cur, p);
      __syncthreads();
    }
  }

  // ---- epilogue: LDS-staged, contiguous row-segment stores (R20) ----
  const size_t obase = (size_t)b * COUT * OUTL;
  #pragma unroll
  for (int p = 0; p < 4; ++p) {
    if (p) __syncthreads();        // p==0: arrived via loop-end barrier
    if ((wid >> 1) == p) {
      const int lrb = (wid & 1) * 32;
      #pragma unroll
      for (int r = 0; r < 16; ++r) {
        const int rowl = (r & 3) + 8 * (r >> 2) + 4 * lh;   // 0..31
        const int grow = p * 64 + lrb + rowl;               // == wid*32+rowl
        Epi[(lrb + rowl) * EPIW + l31]      = acc0[r] + biasS[grow];
        Epi[(lrb + rowl) * EPIW + 32 + l31] = acc1[r] + biasS[grow];
      }
    }
    __syncthreads();
    const int rr = tid >> 3;               // 0..63
    const int c8 = (tid & 7) * 8;          // 0..56
    float* op = out + obase + (size_t)(p * 64 + rr) * OUTL + t0 + c8;
    const f32x4 v0 = *(const f32x4*)&Epi[rr * EPIW + c8];
    const f32x4 v1 = *(const f32x4*)&Epi[rr * EPIW + c8 + 4];
    if (t0 + c8 + 7 < OUTL) {
      *(f32x4*)op = v0;
      *(f32x4*)(op + 4) = v1;
    } else {
      #pragma unroll
      for (int e = 0; e < 4; ++e) {
        if (t0 + c8 + e < OUTL)     op[e]     = v0[e];
        if (t0 + c8 + 4 + e < OUTL) op[4 + e] = v1[e];
      }
    }
  }
}

extern "C" void kernel_launch(void* const* d_in, const int* in_sizes, int n_in,
                              void* d_out, int out_size, void* d_ws, size_t ws_size,
                              hipStream_t stream) {
  const float* x    = (const float*)d_in[0];
  const float* off  = (const float*)d_in[1];
  const float* wgt  = (const float*)d_in[2];
  const float* bias = (const float*)d_in[3];
  float* out  = (float*)d_out;
  short* ap   = (short*)d_ws;   // 393216 B of scratch

  // pack weights into wave-private coalesced A layout (~3 us)
  pack_weights_kernel<<<dim3(NQ * 2 * 8 * 64 / 256), dim3(256), 0, stream>>>(wgt, ap);
  // 8 b x 32 tt x 2 th = 512 blocks (2/CU), 512 threads (8 waves)
  deform_gemm_kernel<<<dim3(512), dim3(512), 0, stream>>>(x, off, ap, bias, out);
}